// Round 12
// baseline (621.392 us; speedup 1.0000x reference)
//
#include <hip/hip_runtime.h>

// ---------------- constants ----------------
#define S_LEN 2048
#define NH 32
#define NKV 8
#define HD 128
#define DMODEL 4096
#define MROWS 4096   // B*S
#define QKVN 6144    // 4096 q + 1024 k + 1024 v output cols

typedef short s16x8 __attribute__((ext_vector_type(8)));
typedef float fx4 __attribute__((ext_vector_type(4)));

__device__ __forceinline__ unsigned short f2bf(float f) {
  unsigned int u = __float_as_uint(f);
  u += 0x7fffu + ((u >> 16) & 1u);   // round-to-nearest-even
  return (unsigned short)(u >> 16);
}
__device__ __forceinline__ float bf2f(unsigned short h) {
  return __uint_as_float(((unsigned int)h) << 16);
}

#define GLDS16(gp, lp)                                                        \
  __builtin_amdgcn_global_load_lds(                                           \
      (const __attribute__((address_space(1))) void*)(gp),                    \
      (__attribute__((address_space(3))) void*)(lp), 16, 0, 0)

#define MFMA16(a, b, c) __builtin_amdgcn_mfma_f32_16x16x32_bf16((a), (b), (c), 0, 0, 0)

// ---------------- fused f32 -> bf16 casts (all 5 tensors, one launch) ----------------
__global__ __launch_bounds__(256) void cast_all_k(const float* __restrict__ hs,
                                                  const float* __restrict__ Wq,
                                                  const float* __restrict__ Wk,
                                                  const float* __restrict__ Wv,
                                                  const float* __restrict__ Wo,
                                                  unsigned short* __restrict__ hsb,
                                                  unsigned short* __restrict__ wqkvb,
                                                  unsigned short* __restrict__ wob) {
  int i = blockIdx.x * 256 + threadIdx.x;
  const float* src;
  unsigned short* dst;
  int off;
  if (i < 4194304)       { src = hs; dst = hsb;                off = 0; }
  else if (i < 8388608)  { src = Wq; dst = wqkvb;              off = 4194304; }
  else if (i < 9437184)  { src = Wk; dst = wqkvb + 16777216;   off = 8388608; }
  else if (i < 10485760) { src = Wv; dst = wqkvb + 20971520;   off = 9437184; }
  else                   { src = Wo; dst = wob;                off = 10485760; }
  int j = i - off;
  float4 v = *(const float4*)(src + (size_t)j * 4);
  ushort4 o;
  o.x = f2bf(v.x); o.y = f2bf(v.y); o.z = f2bf(v.z); o.w = f2bf(v.w);
  *(ushort4*)(dst + (size_t)j * 4) = o;
}

// ---------------- 256x256 8-phase bf16 GEMM (R7-verified) + ldc param ----------------
// Only change vs R11: output column stride `ldc` (pure epilogue addressing),
// so Q and KV projections can write into the strided qkvb[.][6144] layout.
__global__ __launch_bounds__(512, 2) void gemm256(const unsigned short* __restrict__ A,
                                                  const unsigned short* __restrict__ Bt,
                                                  float* __restrict__ Cf,
                                                  unsigned short* __restrict__ Cb,
                                                  int M, int N, int K, int ldc, int bf16out) {
  __shared__ unsigned short Abuf[2][16384];  // [2][256 rows][64 cols]
  __shared__ unsigned short Bbuf[2][16384];
  const int tid = threadIdx.x;
  const int lane = tid & 63;
  const int w = tid >> 6;
  const int wm = w >> 2;   // 0..1
  const int wn = w & 3;    // 0..3

  const int nm = M >> 8;
  const int nn = N >> 8;
  const int rh = nm >> 1;              // rectangle height (tiles)
  const int rw = nn >> 2;              // rectangle width (tiles); nn<4 -> rw>=1 not used here
  const int xcd = blockIdx.x & 7;
  const int l = blockIdx.x >> 3;       // per-XCD sequence
  const int tm = (xcd >> 2) * rh + (l % rh);
  const int tn = (xcd & 3) * rw + (l / rh);

  const int opr = lane & 15;
  const int opk2 = (lane >> 4) << 4;   // byte offset {0,16,32,48}
  const int NT = K >> 6;

  const unsigned short* Agbase = A + (size_t)(tm * 256) * K;
  const unsigned short* Bgbase = Bt + (size_t)(tn * 256) * K;
  const int abase = wm * 16384 + wn * 4096;
  const int bbase = (wn >> 1) * 16384 + (wm * 2 + (wn & 1)) * 4096;

  auto stageA = [&](int bsel, int kt) {
#pragma unroll
    for (int r = 0; r < 4; ++r) {
      const int d = abase + r * 1024 + lane * 16;
      const int row = d >> 7;
      const int u = (d & 127) ^ ((row & 7) << 4);
      GLDS16(Agbase + (size_t)row * K + kt * 64 + (u >> 1), (char*)&Abuf[bsel][0] + d);
    }
  };
  auto stageB = [&](int bsel, int kt) {
#pragma unroll
    for (int r = 0; r < 4; ++r) {
      const int d = bbase + r * 1024 + lane * 16;
      const int row = d >> 7;
      const int u = (d & 127) ^ ((row & 7) << 4);
      GLDS16(Bgbase + (size_t)row * K + kt * 64 + (u >> 1), (char*)&Bbuf[bsel][0] + d);
    }
  };

  fx4 acc[8][4] = {};

  stageA(0, 0); stageB(0, 0);
  stageA(1, 1); stageB(1, 1);
  asm volatile("s_waitcnt vmcnt(8)" ::: "memory");
  __builtin_amdgcn_s_barrier();

#define PH_SYNC()                                            \
  do {                                                       \
    __builtin_amdgcn_s_barrier();                            \
    asm volatile("s_waitcnt lgkmcnt(0)" ::: "memory");       \
    __builtin_amdgcn_sched_barrier(0);                       \
  } while (0)

#pragma unroll 1
  for (int t = 0; t < NT; ++t) {
    const int cur = t & 1;
    const unsigned short* Abc = Abuf[cur];
    const unsigned short* Bbc = Bbuf[cur];
    const int kt2 = (t + 2) & (NT - 1);
    s16x8 a0[8], a1[8], b0[4], b1[4];

#pragma unroll
    for (int i = 0; i < 8; ++i) {
      const int row = wm * 128 + i * 16 + opr;
      a0[i] = *(const s16x8*)((const char*)Abc + row * 128 + (opk2 ^ ((row & 7) << 4)));
    }
#pragma unroll
    for (int j = 0; j < 4; ++j) {
      const int row = wn * 64 + j * 16 + opr;
      b0[j] = *(const s16x8*)((const char*)Bbc + row * 128 + (opk2 ^ ((row & 7) << 4)));
    }
    PH_SYNC();
    __builtin_amdgcn_s_setprio(1);
#pragma unroll
    for (int i = 0; i < 4; ++i)
#pragma unroll
      for (int j = 0; j < 4; ++j) acc[i][j] = MFMA16(a0[i], b0[j], acc[i][j]);
    __builtin_amdgcn_s_setprio(0);
    __builtin_amdgcn_s_barrier();

#pragma unroll
    for (int i = 0; i < 8; ++i) {
      const int row = wm * 128 + i * 16 + opr;
      a1[i] = *(const s16x8*)((const char*)Abc + row * 128 + ((64 + opk2) ^ ((row & 7) << 4)));
    }
    PH_SYNC();
    __builtin_amdgcn_s_setprio(1);
#pragma unroll
    for (int i = 4; i < 8; ++i)
#pragma unroll
      for (int j = 0; j < 4; ++j) acc[i][j] = MFMA16(a0[i], b0[j], acc[i][j]);
    __builtin_amdgcn_s_setprio(0);
    __builtin_amdgcn_s_barrier();

#pragma unroll
    for (int j = 0; j < 4; ++j) {
      const int row = wn * 64 + j * 16 + opr;
      b1[j] = *(const s16x8*)((const char*)Bbc + row * 128 + ((64 + opk2) ^ ((row & 7) << 4)));
    }
    stageA(cur, kt2);
    PH_SYNC();
    __builtin_amdgcn_s_setprio(1);
#pragma unroll
    for (int i = 0; i < 4; ++i)
#pragma unroll
      for (int j = 0; j < 4; ++j) acc[i][j] = MFMA16(a1[i], b1[j], acc[i][j]);
    __builtin_amdgcn_s_setprio(0);
    __builtin_amdgcn_s_barrier();

    stageB(cur, kt2);
    __builtin_amdgcn_s_barrier();
    __builtin_amdgcn_s_setprio(1);
#pragma unroll
    for (int i = 4; i < 8; ++i)
#pragma unroll
      for (int j = 0; j < 4; ++j) acc[i][j] = MFMA16(a1[i], b1[j], acc[i][j]);
    __builtin_amdgcn_s_setprio(0);
    asm volatile("s_waitcnt vmcnt(8)" ::: "memory");
    __builtin_amdgcn_s_barrier();
  }
#undef PH_SYNC

  const int cm = (lane >> 4) << 2;
  const int cn = lane & 15;
#pragma unroll
  for (int i = 0; i < 8; ++i)
#pragma unroll
    for (int j = 0; j < 4; ++j) {
      const int row = tm * 256 + wm * 128 + i * 16 + cm;
      const int col = tn * 256 + wn * 64 + j * 16 + cn;
#pragma unroll
      for (int r = 0; r < 4; ++r) {
        float v = acc[i][j][r];
        if (bf16out) Cb[(size_t)(row + r) * ldc + col] = f2bf(v);
        else         Cf[(size_t)(row + r) * ldc + col] = v;
      }
    }
}

// ---------------- bf16 transpose: out[C][R] = in[R][C]^T (in rows strided) ----------------
__global__ __launch_bounds__(256) void transpose_k(const unsigned short* __restrict__ in,
                                                   unsigned short* __restrict__ out,
                                                   int R, int C, int istride) {
  __shared__ unsigned short T[64][68];
  const int tid = threadIdx.x;
  const int nbc = C >> 6;
  const int br = blockIdx.x / nbc;
  const int bc = blockIdx.x % nbc;
  const int r0 = br << 6, c0 = bc << 6;
#pragma unroll
  for (int i = 0; i < 4; ++i) {
    int row = i * 16 + (tid >> 4);
    int col = (tid & 15) << 2;
    *(ushort4*)&T[row][col] = *(const ushort4*)(in + (size_t)(r0 + row) * istride + c0 + col);
  }
  __syncthreads();
#pragma unroll
  for (int i = 0; i < 4; ++i) {
    int row = i * 16 + (tid >> 4);
    int col = (tid & 15) << 2;
    ushort4 v;
    v.x = T[col + 0][row]; v.y = T[col + 1][row];
    v.z = T[col + 2][row]; v.w = T[col + 3][row];
    *(ushort4*)(out + (size_t)(c0 + row) * R + r0 + col) = v;
  }
}

// ---------------- RoPE cos/sin table ----------------
__global__ __launch_bounds__(256) void rope_tab_k(const float* __restrict__ freqs,
                                                  const int* __restrict__ pos,
                                                  float2* __restrict__ tab) {
  int i = blockIdx.x * 256 + threadIdx.x;  // S*64 = 131072
  int s = i >> 6, d = i & 63;
  float ang = freqs[((size_t)(pos[0] + s) << 6) + d];
  float sv, cv;
  sincosf(ang, &sv, &cv);
  tab[i] = make_float2(cv, sv);
}

// ---------------- RoPE apply, in-place on merged qkv buffer ----------------
__global__ __launch_bounds__(256) void rope_k(unsigned short* __restrict__ qkv,
                                              const float2* __restrict__ tab) {
  int idx = blockIdx.x * 256 + threadIdx.x;  // 4096 * 40 * 64
  int d2 = idx & 63;
  int t = idx >> 6;
  int hh = t % (NH + NKV);
  int row = t / (NH + NKV);
  int s = row & (S_LEN - 1);
  float2 cs = tab[(s << 6) + d2];
  unsigned short* p = qkv + (size_t)row * QKVN +
                      (hh < NH ? hh * HD : DMODEL + (hh - NH) * HD) + (d2 << 1);
  unsigned int xy = *(unsigned int*)p;
  float x1 = bf2f((unsigned short)(xy & 0xffffu));
  float x2 = bf2f((unsigned short)(xy >> 16));
  float o1 = x1 * cs.x - x2 * cs.y;
  float o2 = x1 * cs.y + x2 * cs.x;
  *(unsigned int*)p = (unsigned int)f2bf(o1) | ((unsigned int)f2bf(o2) << 16);
}

// ---------------- MFMA flash attention: R8 math + pipelined staging ----------------
// R12 change (sync/staging only; math identical to R8 -> bit-identical output):
// issue K(t+1) stage right after the "QK reads done" barrier, V(t+1) after the
// "PV reads done" barrier; consume points use counted vmcnt(4) + raw s_barrier
// (never vmcnt(0) in-loop; __syncthreads would drain). Per-wave issue order is
// K,V,K,V,... so at QK-consume outstanding = {V(t),K(t+1)-prev...}<=8 and
// vmcnt(4) == "my 4 K loads landed"; at PV-consume vmcnt(4) == "my 4 V loads
// landed". Wrap-staging keeps counts uniform (tail guard would break vmcnt
// arithmetic). Single K/V buffers: every overwrite is issued only after the
// barrier all waves reach post-read-completion.
__global__ __launch_bounds__(256, 2) void attn_mfma(const unsigned short* __restrict__ qkv,
                                                    const unsigned short* __restrict__ vtb,
                                                    unsigned short* __restrict__ aob) {
  __shared__ alignas(16) unsigned short Ks[64 * 128];    // 16 KB (swizzled)
  __shared__ alignas(16) unsigned short Vts[128 * 64];   // 16 KB (swizzled)
  __shared__ alignas(16) unsigned short Ps[4][32 * 72];  // 18 KB
  const int tid = threadIdx.x;
  const int lane = tid & 63;
  const int w = tid >> 6;
  const int lg = (blockIdx.x & 7) * 128 + (blockIdx.x >> 3);  // grid = 1024
  const int qc = lg & 15;            // 16 q-chunks of 128 rows
  const int hsub = (lg >> 4) & 3;
  const int kvi = (lg >> 6) & 7;
  const int b = lg >> 9;
  const int h = kvi * 4 + hsub;

  const int opr = lane & 15;         // operand row within 16
  const int g = lane >> 4;           // k-subblock 0..3
  const int ak = g * 8;              // operand k offset (shorts)
  const int opk2 = g * 16;           // operand k offset (bytes)
  const int cm = g * 4;              // C/D row base
  const int cn = opr;                // C/D col

  const int qrow0 = b * S_LEN + qc * 128 + w * 32;
  unsigned short* Pw = Ps[w];

  // staging helpers (R8 addressing, parameterized by tile start)
  auto stageK = [&](int t0) {
    const size_t krow0 = (size_t)(b * S_LEN + t0);
#pragma unroll
    for (int i = 0; i < 4; ++i) {
      int d = i * 4096 + tid * 16;
      int row = d >> 8;
      int colb = (d & 255) ^ ((row & 7) << 4);
      GLDS16(qkv + (krow0 + row) * QKVN + DMODEL + kvi * HD + (colb >> 1), (char*)Ks + d);
    }
  };
  auto stageV = [&](int t0) {
#pragma unroll
    for (int i = 0; i < 4; ++i) {
      int d = i * 4096 + tid * 16;
      int row = d >> 7;
      int colb = (d & 127) ^ ((row & 7) << 4);
      GLDS16(vtb + (size_t)(kvi * HD + row) * MROWS + (size_t)(b * S_LEN + t0) + (colb >> 1),
             (char*)Vts + d);
    }
  };

  // ---- Q b-frags hoisted once from global ----
  s16x8 qf[2][4];
#pragma unroll
  for (int qb = 0; qb < 2; ++qb)
#pragma unroll
    for (int kk = 0; kk < 4; ++kk)
      qf[qb][kk] = *(const s16x8*)(qkv + (size_t)(qrow0 + qb * 16 + opr) * QKVN +
                                   h * HD + kk * 32 + ak);

  float m_run[2] = {-1e30f, -1e30f};
  float l_run[2] = {0.f, 0.f};
  fx4 acc[8][2] = {};
  const float scale = 0.08838834764831845f;  // 1/sqrt(128)

  // prologue: issue K(0) then V(0)  [per-wave outstanding: 4K + 4V]
  stageK(0);
  stageV(0);

#pragma unroll 1
  for (int t0 = 0; t0 < S_LEN; t0 += 64) {
    const int t1 = (t0 + 64) & (S_LEN - 1);  // wrap-stage keeps vmcnt counts uniform

    // ---- K(t) consume point: my 4 K loads landed; barrier -> all waves' ----
    asm volatile("s_waitcnt vmcnt(4)" ::: "memory");
    __builtin_amdgcn_sched_barrier(0);
    __builtin_amdgcn_s_barrier();

    // ---- S^T[key][q] = MFMA(K-frag, Q-frag) over d=128 ----
    fx4 st[4][2] = {};
#pragma unroll
    for (int kb2 = 0; kb2 < 4; ++kb2) {
      int krow = kb2 * 16 + opr;
      const char* kbase = (const char*)Ks + krow * 256;
      s16x8 kf[4];
#pragma unroll
      for (int kk = 0; kk < 4; ++kk)
        kf[kk] = *(const s16x8*)(kbase + ((kk * 64 + opk2) ^ ((krow & 7) << 4)));
#pragma unroll
      for (int qb = 0; qb < 2; ++qb)
#pragma unroll
        for (int kk = 0; kk < 4; ++kk)
          st[kb2][qb] = MFMA16(kf[kk], qf[qb][kk], st[kb2][qb]);
    }

    // ---- all waves' QK reads of Ks complete -> safe to overwrite ----
    __builtin_amdgcn_s_barrier();
    stageK(t1);   // issue early; lands during softmax + next-tile latency

    // ---- softmax per q-column (R8 verbatim) ----
    float mloc[2], alpha[2], psum[2];
#pragma unroll
    for (int qb = 0; qb < 2; ++qb) {
      float mm = -1e30f;
#pragma unroll
      for (int kb2 = 0; kb2 < 4; ++kb2)
#pragma unroll
        for (int r = 0; r < 4; ++r) mm = fmaxf(mm, st[kb2][qb][r] * scale);
      mm = fmaxf(mm, __shfl_xor(mm, 16));
      mm = fmaxf(mm, __shfl_xor(mm, 32));
      mloc[qb] = mm;
      float mnew = fmaxf(m_run[qb], mm);
      alpha[qb] = __expf(m_run[qb] - mnew);   // first tile: exp(-huge) = 0
      m_run[qb] = mnew;
      psum[qb] = 0.f;
    }
#pragma unroll
    for (int db = 0; db < 8; ++db)
#pragma unroll
      for (int qb = 0; qb < 2; ++qb)
#pragma unroll
        for (int r = 0; r < 4; ++r) acc[db][qb][r] *= alpha[qb];

#pragma unroll
    for (int kb2 = 0; kb2 < 4; ++kb2)
#pragma unroll
      for (int qb = 0; qb < 2; ++qb)
#pragma unroll
        for (int r = 0; r < 4; ++r) {
          float pv = __expf(st[kb2][qb][r] * scale - m_run[qb]);
          psum[qb] += pv;
          Pw[(qb * 16 + cn) * 72 + kb2 * 16 + cm + r] = f2bf(pv);
        }
#pragma unroll
    for (int qb = 0; qb < 2; ++qb) {
      float s = psum[qb];
      s += __shfl_xor(s, 16);
      s += __shfl_xor(s, 32);
      l_run[qb] = l_run[qb] * alpha[qb] + s;
    }

    // ---- P b-frags (wave-private LDS, in-order within wave) ----
    s16x8 pf[2][2];
#pragma unroll
    for (int qb = 0; qb < 2; ++qb)
#pragma unroll
      for (int tb = 0; tb < 2; ++tb)
        pf[qb][tb] = *(const s16x8*)(Pw + (qb * 16 + opr) * 72 + tb * 32 + ak);

    // ---- V(t) consume point: outstanding = K(t1) 4 + V(t) -> vmcnt(4) = V landed ----
    asm volatile("s_waitcnt vmcnt(4)" ::: "memory");
    __builtin_amdgcn_sched_barrier(0);
    __builtin_amdgcn_s_barrier();

    // ---- O^T += MFMA(V^T-frag, P-frag) over t=64 ----
#pragma unroll
    for (int db = 0; db < 8; ++db) {
      int vrow = db * 16 + opr;
      const char* vbase = (const char*)Vts + vrow * 128;
      s16x8 vf[2];
#pragma unroll
      for (int tb = 0; tb < 2; ++tb)
        vf[tb] = *(const s16x8*)(vbase + ((tb * 64 + opk2) ^ ((vrow & 7) << 4)));
#pragma unroll
      for (int qb = 0; qb < 2; ++qb)
#pragma unroll
        for (int tb = 0; tb < 2; ++tb)
          acc[db][qb] = MFMA16(vf[tb], pf[qb][tb], acc[db][qb]);
    }

    // ---- all waves' PV reads of Vts complete -> safe to overwrite ----
    __builtin_amdgcn_s_barrier();
    stageV(t1);   // lands during next tile's QK^T
  }

  // ---- epilogue: normalize per q, pack 4 consecutive d -> 8B ----
  float inv[2] = {1.0f / l_run[0], 1.0f / l_run[1]};
#pragma unroll
  for (int db = 0; db < 8; ++db)
#pragma unroll
    for (int qb = 0; qb < 2; ++qb) {
      ushort4 o;
      o.x = f2bf(acc[db][qb][0] * inv[qb]);
      o.y = f2bf(acc[db][qb][1] * inv[qb]);
      o.z = f2bf(acc[db][qb][2] * inv[qb]);
      o.w = f2bf(acc[db][qb][3] * inv[qb]);
      *(ushort4*)(aob + (size_t)(qrow0 + qb * 16 + cn) * DMODEL + h * HD + db * 16 + cm) = o;
    }
}

// ---------------- launch ----------------
extern "C" void kernel_launch(void* const* d_in, const int* in_sizes, int n_in,
                              void* d_out, int out_size, void* d_ws, size_t ws_size,
                              hipStream_t stream) {
  const float* hs = (const float*)d_in[0];
  const float* fr = (const float*)d_in[1];
  const float* Wq = (const float*)d_in[2];
  const float* Wk = (const float*)d_in[3];
  const float* Wv = (const float*)d_in[4];
  const float* Wo = (const float*)d_in[5];
  const int* pos = (const int*)d_in[6];
  float* out = (float*)d_out;

  // workspace (bf16 elems), total 83,886,080 shorts = 167.8 MB
  unsigned short* w = (unsigned short*)d_ws;
  unsigned short* hsb   = w; w += 16777216;  // [4096,4096] hs bf16 (tab reuses after QKV gemm)
  unsigned short* wqkvb = w; w += 25165824;  // [6144,4096] Wq|Wk|Wv  (aob+vtb reuse after gemm)
  unsigned short* wob   = w; w += 16777216;  // [4096,4096]
  unsigned short* qkvb  = w; w += 25165824;  // [4096,6144] q|k|v per row (rope in-place)
  unsigned short* aob = wqkvb;               // [4096,4096] attn out
  unsigned short* vtb = wqkvb + 16777216;    // [1024,4096] V^T
  float2* tab = (float2*)hsb;                // [2048*64] cos/sin

  if (ws_size < (size_t)83886080 * 2) return;

  cast_all_k<<<57344, 256, 0, stream>>>(hs, Wq, Wk, Wv, Wo, hsb, wqkvb, wob);

  // Q projection: [4096,4096] x [4096,4096]^T -> qkvb cols 0..4095 (grid 256 = 1 clean round)
  gemm256<<<256, 512, 0, stream>>>(hsb, wqkvb, nullptr, qkvb, MROWS, DMODEL, DMODEL, QKVN, 1);
  // KV projection: [4096,4096] x [2048,4096]^T -> qkvb cols 4096..6143 (grid 128)
  gemm256<<<128, 512, 0, stream>>>(hsb, wqkvb + (size_t)DMODEL * DMODEL, nullptr,
                                   qkvb + DMODEL, MROWS, 2048, DMODEL, QKVN, 1);

  rope_tab_k<<<512, 256, 0, stream>>>(fr, pos, tab);   // hsb dead now
  rope_k<<<40960, 256, 0, stream>>>(qkvb, tab);

  transpose_k<<<1024, 256, 0, stream>>>(qkvb + 5120, vtb, MROWS, 1024, QKVN);  // V -> V^T

  attn_mfma<<<1024, 256, 0, stream>>>(qkvb, vtb, aob);

  // output projection: [4096,4096] x [4096,4096]^T -> f32 out (grid 256 clean)
  gemm256<<<256, 512, 0, stream>>>(aob, wob, out, nullptr, MROWS, DMODEL, DMODEL, DMODEL, 0);
}